// Round 8
// baseline (673.843 us; speedup 1.0000x reference)
//
#include <hip/hip_runtime.h>

// B=1024, T=128, F=1024, Z=256, TXT=768, H=8, d=128
#define EPS 1e-5f

typedef __bf16 bf16x8 __attribute__((ext_vector_type(8)));
typedef float f32x4 __attribute__((ext_vector_type(4)));
typedef ushort ushort8 __attribute__((ext_vector_type(8)));

static __device__ __forceinline__ ushort f2bf(float x) {
    union { float f; unsigned u; } v; v.f = x;
    unsigned r = v.u + 0x7fffu + ((v.u >> 16) & 1u);  // RNE
    return (ushort)(r >> 16);
}
static __device__ __forceinline__ float bf2f(ushort u) {
    union { unsigned u32; float f; } v; v.u32 = (unsigned)u << 16;
    return v.f;
}

// ======================================================================
// gemm_bb: C = scale * (A_bf16 @ W_bf16^T) + bias(f32)
// Tile 64x64, BK=128 (8 steps @K=1024 -> half the barriers of BK=64),
// 4 waves (2x2 of 32x32), 2x2 16x16x32 frags, 16 MFMA per staging/wave.
// Register-prefetch pipeline: next K-tile loads issued during MFMA.
// LDS rows padded to 136 ushort (row stride 4 banks -> worst 2-way = free).
// ======================================================================
template<int OB>
__global__ __launch_bounds__(256)
void gemm_bb(const ushort* __restrict__ A, int lda, int Aoffz,
             const ushort* __restrict__ W, int ldw, int Woffz,
             void* __restrict__ Cv, int ldc, int Coffz,
             const float* __restrict__ bias, int boffz,
             float scale, int K)
{
    const int z = blockIdx.z;
    A += (size_t)z * Aoffz;
    W += (size_t)z * Woffz;
    const int bm = blockIdx.y * 64, bn = blockIdx.x * 64;

    __shared__ ushort As[64][136];
    __shared__ ushort Bs[64][136];

    const int tid  = threadIdx.x;
    const int lane = tid & 63, wv = tid >> 6;
    const int wm = (wv >> 1) * 32, wn = (wv & 1) * 32;

    const int srow = tid >> 2;            // 0..63
    const int scol = (tid & 3) * 32;      // 0,32,64,96
    const ushort* Agp = A + (size_t)(bm + srow) * lda + scol;
    const ushort* Wgp = W + (size_t)(bn + srow) * ldw + scol;

    const int fr = lane & 15, fk = (lane >> 4) * 8;

    f32x4 acc[2][2] = {};

    // prologue: prefetch K-tile 0 (4x ushort8 per operand)
    ushort8 a[4], b[4];
    #pragma unroll
    for (int j = 0; j < 4; ++j) {
        a[j] = *(const ushort8*)(Agp + 8 * j);
        b[j] = *(const ushort8*)(Wgp + 8 * j);
    }

    for (int kt = 0; kt < K; kt += 128) {
        #pragma unroll
        for (int j = 0; j < 4; ++j) {
            *(ushort8*)&As[srow][scol + 8 * j] = a[j];
            *(ushort8*)&Bs[srow][scol + 8 * j] = b[j];
        }
        __syncthreads();
        if (kt + 128 < K) {   // prefetch next tile; flies under MFMA below
            #pragma unroll
            for (int j = 0; j < 4; ++j) {
                a[j] = *(const ushort8*)(Agp + kt + 128 + 8 * j);
                b[j] = *(const ushort8*)(Wgp + kt + 128 + 8 * j);
            }
        }
        #pragma unroll
        for (int ks = 0; ks < 128; ks += 32) {
            bf16x8 af0 = *(const bf16x8*)&As[wm + fr][ks + fk];
            bf16x8 af1 = *(const bf16x8*)&As[wm + 16 + fr][ks + fk];
            bf16x8 bf0 = *(const bf16x8*)&Bs[wn + fr][ks + fk];
            bf16x8 bf1 = *(const bf16x8*)&Bs[wn + 16 + fr][ks + fk];
            acc[0][0] = __builtin_amdgcn_mfma_f32_16x16x32_bf16(af0, bf0, acc[0][0], 0, 0, 0);
            acc[0][1] = __builtin_amdgcn_mfma_f32_16x16x32_bf16(af0, bf1, acc[0][1], 0, 0, 0);
            acc[1][0] = __builtin_amdgcn_mfma_f32_16x16x32_bf16(af1, bf0, acc[1][0], 0, 0, 0);
            acc[1][1] = __builtin_amdgcn_mfma_f32_16x16x32_bf16(af1, bf1, acc[1][1], 0, 0, 0);
        }
        __syncthreads();
    }

    const int rbase = (lane >> 4) * 4;
    #pragma unroll
    for (int mi = 0; mi < 2; ++mi) {
        #pragma unroll
        for (int ni = 0; ni < 2; ++ni) {
            const int col = bn + wn + ni * 16 + fr;
            const float bvv = bias ? (bias + (size_t)z * boffz)[col] : 0.f;
            #pragma unroll
            for (int r = 0; r < 4; ++r) {
                const int row = bm + wm + mi * 16 + rbase + r;
                const float val = acc[mi][ni][r] * scale + bvv;
                if (OB) {
                    ((ushort*)Cv)[(size_t)z * Coffz + (size_t)row * ldc + col] = f2bf(val);
                } else {
                    ((float*)Cv)[(size_t)z * Coffz + (size_t)row * ldc + col] = val;
                }
            }
        }
    }
}

// ======================================================================
// cvt_all: every f32->bf16 conversion (weights + x + z) AND the Wk
// transpose in ONE kernel.  Blocks 0..5631: elementwise cvt segments.
// Blocks 5632..6399: Wk [1024,768] -> WkT [8][768][128] bf16 (32x32 LDS
// transpose tiles, flattened from grid (24,4,8)).  Grid: 6400 x 256.
// ======================================================================
__global__ __launch_bounds__(256)
void cvt_all(const float* __restrict__ Wl, const float* __restrict__ Wq,
             const float* __restrict__ Wo, const float* __restrict__ Wv,
             const float* __restrict__ Wg, const float* __restrict__ Wb,
             const float* __restrict__ x,  const float* __restrict__ zc,
             const float* __restrict__ bg, const float* __restrict__ bb,
             const float* __restrict__ Wk,
             ushort* __restrict__ WlB, ushort* __restrict__ WqB,
             ushort* __restrict__ WoB, ushort* __restrict__ WvB,
             ushort* __restrict__ WgbB, ushort* __restrict__ xB,
             ushort* __restrict__ zB, float* __restrict__ bgb,
             ushort* __restrict__ WkT)
{
    __shared__ ushort s[32][33];
    const int bx = blockIdx.x;
    if (bx >= 5632) {   // ---- transpose path ----
        const int tb = bx - 5632;
        const int h  = tb / 96;
        const int rem = tb % 96;
        const int c0 = (rem % 24) * 32, d0 = (rem / 24) * 32;
        const int tx = threadIdx.x & 31, ty = threadIdx.x >> 5;
        #pragma unroll
        for (int i = 0; i < 4; ++i) {
            int d = d0 + ty + i * 8;
            s[ty + i * 8][tx] = f2bf(Wk[(size_t)(h * 128 + d) * 768 + c0 + tx]);
        }
        __syncthreads();
        #pragma unroll
        for (int i = 0; i < 4; ++i) {
            int c = c0 + ty + i * 8;
            WkT[((size_t)h * 768 + c) * 128 + d0 + tx] = s[tx][ty + i * 8];
        }
        return;
    }
    int gid = bx * 256 + threadIdx.x;
    if (gid < 512) {  // bgb: 2048 f32 = 512 float4
        f32x4 v = (gid < 256) ? *(const f32x4*)(bg + gid * 4)
                              : *(const f32x4*)(bb + (gid - 256) * 4);
        *(f32x4*)(bgb + gid * 4) = v;
    }
    const float* src; ushort* dst; int off;
    if      (gid <  262144) { src = Wl; dst = WlB;           off = gid;          }
    else if (gid <  524288) { src = Wq; dst = WqB;           off = gid - 262144; }
    else if (gid <  786432) { src = Wo; dst = WoB;           off = gid - 524288; }
    else if (gid <  983040) { src = Wv; dst = WvB;           off = gid - 786432; }
    else if (gid < 1048576) { src = Wg; dst = WgbB;          off = gid - 983040; }
    else if (gid < 1114112) { src = Wb; dst = WgbB + 262144; off = gid - 1048576;}
    else if (gid < 1376256) { src = x;  dst = xB;            off = gid - 1114112;}
    else if (gid < 1441792) { src = zc; dst = zB;            off = gid - 1376256;}
    else return;
    f32x4 v = *(const f32x4*)(src + (size_t)off * 4);
    ushort4 o;
    o.x = f2bf(v[0]); o.y = f2bf(v[1]); o.z = f2bf(v[2]); o.w = f2bf(v[3]);
    *(ushort4*)(dst + (size_t)off * 4) = o;
}

// ======================================================================
// block reduce (2 values, 256 thr)
// ======================================================================
__device__ inline void block_reduce2(float& a, float& b, float* sred)
{
    #pragma unroll
    for (int off = 32; off; off >>= 1) {
        a += __shfl_xor(a, off);
        b += __shfl_xor(b, off);
    }
    int w = threadIdx.x >> 6, lane = threadIdx.x & 63;
    if (lane == 0) { sred[w * 2] = a; sred[w * 2 + 1] = b; }
    __syncthreads();
    a = sred[0] + sred[2] + sred[4] + sred[6];
    b = sred[1] + sred[3] + sred[5] + sred[7];
}

// ======================================================================
// rowops1: outb(bf16) = LN(h1)*g+b then FiLM.  gamma|beta in GB [B,2048].
// ======================================================================
__global__ __launch_bounds__(256)
void rowops1(const float* __restrict__ h1, const float* __restrict__ gb,
             const float* __restrict__ g, const float* __restrict__ bta,
             ushort* __restrict__ outb)
{
    __shared__ float sred[8];
    int b = blockIdx.x, tid = threadIdx.x;
    const float4 v = ((const float4*)(h1 + (size_t)b * 1024))[tid];
    float s  = v.x + v.y + v.z + v.w;
    float ss = v.x * v.x + v.y * v.y + v.z * v.z + v.w * v.w;
    block_reduce2(s, ss, sred);
    float mu  = s * (1.f / 1024.f);
    float var = ss * (1.f / 1024.f) - mu * mu;
    float rs  = rsqrtf(var + EPS);
    float4 gv = ((const float4*)g)[tid];
    float4 bv = ((const float4*)bta)[tid];
    float4 ga = ((const float4*)(gb + (size_t)b * 2048))[tid];
    float4 be = ((const float4*)(gb + (size_t)b * 2048 + 1024))[tid];
    ushort4 o;
    o.x = f2bf(((v.x - mu) * rs * gv.x + bv.x) * (1.f + ga.x) + be.x);
    o.y = f2bf(((v.y - mu) * rs * gv.y + bv.y) * (1.f + ga.y) + be.y);
    o.z = f2bf(((v.z - mu) * rs * gv.z + bv.z) * (1.f + ga.z) + be.z);
    o.w = f2bf(((v.w - mu) * rs * gv.w + bv.w) * (1.f + ga.w) + be.w);
    ((ushort4*)(outb + (size_t)b * 1024))[tid] = o;
}

// ======================================================================
// rowops2: final = gelu(outb + LN(attn_out)*g+b)
// ======================================================================
__global__ __launch_bounds__(256)
void rowops2(const ushort* __restrict__ outb, const float* __restrict__ ao,
             const float* __restrict__ g, const float* __restrict__ bta,
             float* __restrict__ dst)
{
    __shared__ float sred[8];
    int b = blockIdx.x, tid = threadIdx.x;
    const float4 v = ((const float4*)(ao + (size_t)b * 1024))[tid];
    float s  = v.x + v.y + v.z + v.w;
    float ss = v.x * v.x + v.y * v.y + v.z * v.z + v.w * v.w;
    block_reduce2(s, ss, sred);
    float mu  = s * (1.f / 1024.f);
    float var = ss * (1.f / 1024.f) - mu * mu;
    float rs  = rsqrtf(var + EPS);
    float4 gv = ((const float4*)g)[tid];
    float4 bv = ((const float4*)bta)[tid];
    ushort4 ou = ((const ushort4*)(outb + (size_t)b * 1024))[tid];
    float y0 = bf2f(ou.x) + ((v.x - mu) * rs * gv.x + bv.x);
    float y1 = bf2f(ou.y) + ((v.y - mu) * rs * gv.y + bv.y);
    float y2 = bf2f(ou.z) + ((v.z - mu) * rs * gv.z + bv.z);
    float y3 = bf2f(ou.w) + ((v.w - mu) * rs * gv.w + bv.w);
    float4 o;
    o.x = 0.5f * y0 * (1.f + erff(y0 * 0.70710678118654752f));
    o.y = 0.5f * y1 * (1.f + erff(y1 * 0.70710678118654752f));
    o.z = 0.5f * y2 * (1.f + erff(y2 * 0.70710678118654752f));
    o.w = 0.5f * y3 * (1.f + erff(y3 * 0.70710678118654752f));
    ((float4*)(dst + (size_t)b * 1024))[tid] = o;
}

// ======================================================================
// attn_fused with T14 async-STAGE split:
//   prologue: load stage-0 tf tile into 24 f32x4 regs.
//   per stage: barrier -> cvt+write regs to TF LDS -> barrier ->
//              ISSUE stage s+1 loads (fly under compute) ->
//              scores MFMA (waves 0/1) -> online softmax -> VALU PV.
// tf read exactly once. LDS ~75 KB -> 2 blocks/CU.
// ======================================================================
__global__ __launch_bounds__(256)
void attn_fused(const float* __restrict__ tf, const ushort* __restrict__ qt,
                const int* __restrict__ att, ushort* __restrict__ ctxtf)
{
    const int b = blockIdx.x;
    const int tid = threadIdx.x, lane = tid & 63, wv = tid >> 6;

    __shared__ ushort qtS[16][776];
    __shared__ ushort TF[32][776];
    __shared__ float s_sc[8][32];
    __shared__ float ps[8][32];

    const float*  tfb = tf + (size_t)b * 98304;
    const ushort* qtb = qt + (size_t)b * 6144;

    // ---- stage qt rows 0-7 (bf16 copy), zero rows 8-15 ----
    {
        const int r  = tid >> 5;             // 0..7
        const int c0 = (tid & 31) * 24;      // 24 cols per thread
        #pragma unroll
        for (int j = 0; j < 3; ++j)
            *(ushort8*)&qtS[r][c0 + 8 * j] = *(const ushort8*)&qtb[r * 768 + c0 + 8 * j];
        const ushort8 z8 = {0,0,0,0,0,0,0,0};
        #pragma unroll
        for (int j = 0; j < 3; ++j)
            *(ushort8*)&qtS[8 + r][c0 + 8 * j] = z8;
    }

    float acc[2][3][4] = {};
    float mrun = -INFINITY, srun = 0.f;
    const int fr = lane & 15, fko = (lane >> 4) * 8;
    const int hloc = lane >> 5, tl = lane & 31;
    const int h_own = 2 * wv + hloc;
    const int h0 = 2 * wv;

    // ---- T14 prologue: load stage 0 into regs ----
    const int pr  = tid >> 3;             // 0..31 (row within tile)
    const int pc0 = (tid & 7) * 96;       // 96 cols per thread
    const float* srcp = tfb + (size_t)pr * 768 + pc0;
    f32x4 pf[24];
    #pragma unroll
    for (int j = 0; j < 24; ++j) pf[j] = *(const f32x4*)(srcp + 4 * j);

    for (int s = 0; s < 4; ++s) {
        __syncthreads();   // prev stage PV done with TF
        // ---- write prefetched regs (cvt f32->bf16) to TF ----
        #pragma unroll
        for (int j = 0; j < 24; ++j) {
            ushort4 o;
            o.x = f2bf(pf[j][0]); o.y = f2bf(pf[j][1]);
            o.z = f2bf(pf[j][2]); o.w = f2bf(pf[j][3]);
            *(ushort4*)&TF[pr][pc0 + 4 * j] = o;
        }
        __syncthreads();   // TF (and qtS) ready
        // ---- issue next stage's loads; they fly under compute below ----
        if (s < 3) {
            const float* srcn = srcp + (size_t)(s + 1) * 32 * 768;
            #pragma unroll
            for (int j = 0; j < 24; ++j) pf[j] = *(const f32x4*)(srcn + 4 * j);
        }
        // ---- scores: waves 0,1 -> s_sc[h][0..31] ----
        if (wv < 2) {
            f32x4 sacc = {0.f, 0.f, 0.f, 0.f};
            #pragma unroll
            for (int ks = 0; ks < 768; ks += 32) {
                bf16x8 aq = *(const bf16x8*)&qtS[fr][ks + fko];
                bf16x8 bt = *(const bf16x8*)&TF[wv * 16 + fr][ks + fko];
                sacc = __builtin_amdgcn_mfma_f32_16x16x32_bf16(aq, bt, sacc, 0, 0, 0);
            }
            if (lane < 32) {
                const int hbase = (lane >> 4) * 4;
                #pragma unroll
                for (int r = 0; r < 4; ++r)
                    s_sc[hbase + r][wv * 16 + (lane & 15)] = sacc[r];
            }
        }
        __syncthreads();   // scores ready
        // ---- online softmax: wave owns heads 2wv (lanes<32), 2wv+1 ----
        {
            const int mask = att[b * 128 + s * 32 + tl];
            float sv = mask ? s_sc[h_own][tl] : -INFINITY;
            float mx = sv;
            mx = fmaxf(mx, __shfl_xor(mx, 16));
            mx = fmaxf(mx, __shfl_xor(mx, 8));
            mx = fmaxf(mx, __shfl_xor(mx, 4));
            mx = fmaxf(mx, __shfl_xor(mx, 2));
            mx = fmaxf(mx, __shfl_xor(mx, 1));
            float mnew = fmaxf(mrun, mx);
            float p = mask ? __expf(sv - mnew) : 0.f;
            float f = (mnew == -INFINITY) ? 1.f : __expf(mrun - mnew);
            float psum = p;
            psum += __shfl_xor(psum, 16);
            psum += __shfl_xor(psum, 8);
            psum += __shfl_xor(psum, 4);
            psum += __shfl_xor(psum, 2);
            psum += __shfl_xor(psum, 1);
            srun = srun * f + psum;
            mrun = mnew;
            ps[h_own][tl] = p;
            const float f0 = __shfl(f, 0);
            const float f1 = __shfl(f, 32);
            #pragma unroll
            for (int k = 0; k < 3; ++k)
                #pragma unroll
                for (int e = 0; e < 4; ++e) {
                    acc[0][k][e] *= f0;
                    acc[1][k][e] *= f1;
                }
        }
        // ---- PV (same-wave ps, no barrier) ----
        {
            #pragma unroll 8
            for (int t = 0; t < 32; ++t) {
                const float p0 = ps[h0][t];
                const float p1 = ps[h0 + 1][t];
                #pragma unroll
                for (int k = 0; k < 3; ++k) {
                    ushort4 u = *(const ushort4*)&TF[t][4 * lane + 256 * k];
                    float x0 = bf2f(u.x), x1 = bf2f(u.y), x2 = bf2f(u.z), x3 = bf2f(u.w);
                    acc[0][k][0] += p0 * x0; acc[0][k][1] += p0 * x1;
                    acc[0][k][2] += p0 * x2; acc[0][k][3] += p0 * x3;
                    acc[1][k][0] += p1 * x0; acc[1][k][1] += p1 * x1;
                    acc[1][k][2] += p1 * x2; acc[1][k][3] += p1 * x3;
                }
            }
        }
    }

    // ---- normalize + write bf16 ----
    const float sum0 = __shfl(srun, 0);
    const float sum1 = __shfl(srun, 32);
    const float i0 = 1.f / sum0, i1 = 1.f / sum1;
    #pragma unroll
    for (int k = 0; k < 3; ++k) {
        ushort4 o0, o1;
        o0.x = f2bf(acc[0][k][0] * i0); o0.y = f2bf(acc[0][k][1] * i0);
        o0.z = f2bf(acc[0][k][2] * i0); o0.w = f2bf(acc[0][k][3] * i0);
        o1.x = f2bf(acc[1][k][0] * i1); o1.y = f2bf(acc[1][k][1] * i1);
        o1.z = f2bf(acc[1][k][2] * i1); o1.w = f2bf(acc[1][k][3] * i1);
        *(ushort4*)&ctxtf[(size_t)b * 6144 + (size_t)h0 * 768 + 4 * lane + 256 * k] = o0;
        *(ushort4*)&ctxtf[(size_t)b * 6144 + (size_t)(h0 + 1) * 768 + 4 * lane + 256 * k] = o1;
    }
}

// ======================================================================
// launch
// ======================================================================
extern "C" void kernel_launch(void* const* d_in, const int* in_sizes, int n_in,
                              void* d_out, int out_size, void* d_ws, size_t ws_size,
                              hipStream_t stream)
{
    const float* x    = (const float*)d_in[0];
    const float* zc   = (const float*)d_in[1];
    const float* tf   = (const float*)d_in[2];
    const int*   att  = (const int*)d_in[3];
    const float* Wg   = (const float*)d_in[4];
    const float* bg   = (const float*)d_in[5];
    const float* Wb   = (const float*)d_in[6];
    const float* bb   = (const float*)d_in[7];
    const float* Wl   = (const float*)d_in[8];
    const float* bl   = (const float*)d_in[9];
    const float* ln1g = (const float*)d_in[10];
    const float* ln1b = (const float*)d_in[11];
    const float* Wq   = (const float*)d_in[12];
    const float* bq   = (const float*)d_in[13];
    const float* Wk   = (const float*)d_in[14];
    // d_in[15] = bk: softmax-shift-invariant, cancels exactly.
    const float* Wv   = (const float*)d_in[16];
    const float* bv   = (const float*)d_in[17];
    const float* Wo   = (const float*)d_in[18];
    const float* bo   = (const float*)d_in[19];
    const float* ln2g = (const float*)d_in[20];
    const float* ln2b = (const float*)d_in[21];

    float* ws = (float*)d_ws;
    const size_t M1 = 1u << 20;
    float* H1  = ws;              // [B,F] f32
    float* GB  = ws + 1 * M1;     // [B,2048] f32 gamma|beta
    float* AO  = ws + 3 * M1;     // [B,F] f32
    float* bgb = ws + 4 * M1;     // [2048] f32 bg|bb

    ushort* u = (ushort*)(ws + 5 * M1);
    ushort* WlB  = u;                       // 1M
    ushort* WqB  = u + 1 * M1;              // 1M
    ushort* WoB  = u + 2 * M1;              // 1M
    ushort* WvB  = u + 3 * M1;              // 768K
    ushort* WgbB = u + 3 * M1 + 786432;     // 512K [Wg|Wb][2048,256]
    ushort* WkT  = u + 3 * M1 + 1310720;    // 768K [8][768][128]
    ushort* xB   = u + 5 * M1;              // 1M
    ushort* zB   = u + 6 * M1;              // 256K
    ushort* OUTB = u + 6 * M1 + 262144;     // 1M  bf16 modulated output
    ushort* Q    = u + 7 * M1 + 262144;     // 1M  bf16
    ushort* QT   = u + 8 * M1 + 262144;     // 6M  bf16 [B,8,768]
    ushort* CTXB = u + 14 * M1 + 262144;    // 6M  bf16 [B,8,768]
    ushort* CTX  = u + 20 * M1 + 262144;    // 1M  bf16 [B,F]

    dim3 blk(256);

    // ---- prep (1 dispatch: cvt + Wk transpose) ----
    cvt_all<<<dim3(6400), blk, 0, stream>>>(Wl, Wq, Wo, Wv, Wg, Wb, x, zc, bg, bb, Wk,
                                            WlB, WqB, WoB, WvB, WgbB, xB, zB, bgb, WkT);

    // ---- h1 = x @ Wl^T + bl  (f32 out) ----
    gemm_bb<0><<<dim3(16, 16, 1), blk, 0, stream>>>(xB, 1024, 0, WlB, 1024, 0,
        (void*)H1, 1024, 0, bl, 0, 1.f, 1024);
    // ---- [gamma|beta] = z @ [Wg|Wb]^T + [bg|bb]  (f32 out) ----
    gemm_bb<0><<<dim3(32, 16, 1), blk, 0, stream>>>(zB, 256, 0, WgbB, 256, 0,
        (void*)GB, 2048, 0, bgb, 0, 1.f, 256);
    // ---- outb = LN(h1)*(1+gamma)+beta  (bf16) ----
    rowops1<<<dim3(1024), blk, 0, stream>>>(H1, GB, ln1g, ln1b, OUTB);
    // ---- q = outb @ Wq^T + bq  (bf16 out) ----
    gemm_bb<1><<<dim3(16, 16, 1), blk, 0, stream>>>(OUTB, 1024, 0, WqB, 1024, 0,
        (void*)Q, 1024, 0, bq, 0, 1.f, 1024);
    // ---- qt[b,h,:] = (1/sqrt(128)) * q[b,h,:] @ Wk_h  (bf16 out) ----
    gemm_bb<1><<<dim3(12, 16, 8), blk, 0, stream>>>(Q, 1024, 128, WkT, 128, 98304,
        (void*)QT, 6144, 768, nullptr, 0, 0.08838834764831845f, 128);
    // ---- fused single-pass attention (bf16 out) ----
    attn_fused<<<dim3(1024), blk, 0, stream>>>(tf, QT, att, CTXB);
    // ---- ctx = ctxtf @ Wv_h^T + bv  (bf16 out) ----
    gemm_bb<1><<<dim3(2, 16, 8), blk, 0, stream>>>(CTXB, 6144, 768, WvB, 768, 98304,
        (void*)CTX, 1024, 128, bv, 128, 1.f, 768);
    // ---- attn_out = ctx @ Wo^T + bo  (f32 out) ----
    gemm_bb<0><<<dim3(16, 16, 1), blk, 0, stream>>>(CTX, 1024, 0, WoB, 1024, 0,
        (void*)AO, 1024, 0, bo, 0, 1.f, 1024);
    // ---- final = gelu(outb + LN(attn_out)) ----
    rowops2<<<dim3(1024), blk, 0, stream>>>(OUTB, AO, ln2g, ln2b, (float*)d_out);
}